// Round 8
// baseline (1836.070 us; speedup 1.0000x reference)
//
#include <hip/hip_runtime.h>
#include <hip/hip_bf16.h>

#define TSTEPS 32
#define HDIM 1024

typedef __bf16 bf16x8 __attribute__((ext_vector_type(8)));
typedef float f32x4 __attribute__((ext_vector_type(4)));
typedef unsigned short u16;
typedef unsigned int u32;

__device__ __forceinline__ u32 f2bf(float f) {
    u32 u = __float_as_uint(f);
    return (u + 0x7FFFu + ((u >> 16) & 1u)) >> 16;   // RNE
}
__device__ __forceinline__ u32 pack2(float a, float b) {
    return f2bf(a) | (f2bf(b) << 16);
}
__device__ __forceinline__ float sigf(float x) { return 1.f / (1.f + __expf(-x)); }
__device__ __forceinline__ float tanhfast(float x) { return 1.f - 2.f / (1.f + __expf(2.f * x)); }

__device__ __forceinline__ void sbar()    { __builtin_amdgcn_s_barrier(); }
__device__ __forceinline__ void vmcnt12() { asm volatile("s_waitcnt vmcnt(12)" ::: "memory"); }
__device__ __forceinline__ void vmcnt8()  { asm volatile("s_waitcnt vmcnt(8)"  ::: "memory"); }
__device__ __forceinline__ void vmcnt0()  { asm volatile("s_waitcnt vmcnt(0)"  ::: "memory"); }
__device__ __forceinline__ void lgkm0()   { asm volatile("s_waitcnt lgkmcnt(0)" ::: "memory"); }

// ws: Wp (8MB) @0 | hb0 (4MB) @8M | hb1 (4MB) @12M | cbuf (8MB) @16M | p0 @24M

// Permuted bf16 W' with the fc path folded in (rank-1 update):
//   W'[jg][k] = Whh[jg][k] + Wih[jg,0]*fcW[k]
// Linear gload_lds staging => XOR-swizzled LDS image.
__global__ void k_prep_w(const float* __restrict__ W, const float* __restrict__ Wih,
                         const float* __restrict__ fcW, uint4* __restrict__ Wp) {
    int o = blockIdx.x * 256 + threadIdx.x;          // 524288 16B units
    int colT = o >> 14, c = (o >> 10) & 15, l = o & 1023;
    int bc = l >> 3, u = l & 7;
    int jg = ((bc >> 5) << 10) + colT * 32 + (bc & 31);
    int kk = c * 64 + ((u ^ (bc & 7)) << 3);
    const float4* src  = (const float4*)(W + (size_t)jg * HDIM + kk);
    const float4* fsrc = (const float4*)(fcW + kk);
    float wx = Wih[2 * jg];
    float4 lo = src[0], hi = src[1], fl = fsrc[0], fh = fsrc[1];
    lo.x += wx * fl.x; lo.y += wx * fl.y; lo.z += wx * fl.z; lo.w += wx * fl.w;
    hi.x += wx * fh.x; hi.y += wx * fh.y; hi.z += wx * fh.z; hi.w += wx * fh.w;
    uint4 pk = { pack2(lo.x, lo.y), pack2(lo.z, lo.w), pack2(hi.x, hi.y), pack2(hi.z, hi.w) };
    Wp[o] = pk;
}

__global__ void k_prep_state(const float* __restrict__ h0, const float* __restrict__ c0,
                             u16* __restrict__ hb, float* __restrict__ c) {
    int i = blockIdx.x * 256 + threadIdx.x;          // x4 elems
    float4 v = ((const float4*)h0)[i];
    ushort4 o = { (u16)f2bf(v.x), (u16)f2bf(v.y), (u16)f2bf(v.z), (u16)f2bf(v.w) };
    ((ushort4*)hb)[i] = o;
    ((float4*)c)[i] = ((const float4*)c0)[i];
}

// p0[n] = fcW . h0[n,:] + fcb  (t=0 correction for the folded fc path)
__global__ void k_prep_p0(const float* __restrict__ h0, const float* __restrict__ fcW,
                          const float* __restrict__ fcb, float* __restrict__ p0) {
    int n = blockIdx.x * 4 + (threadIdx.x >> 6);
    int lane = threadIdx.x & 63;
    const float* hr = h0 + (size_t)n * HDIM;
    float s = 0.f;
#pragma unroll
    for (int i = 0; i < 16; ++i)
        s += fcW[lane + 64 * i] * hr[lane + 64 * i];
    s += __shfl_xor(s, 1);  s += __shfl_xor(s, 2);  s += __shfl_xor(s, 4);
    s += __shfl_xor(s, 8);  s += __shfl_xor(s, 16); s += __shfl_xor(s, 32);
    if (lane == 0) p0[n] = s + fcb[0];
}

__global__ void k_init_out(float* __restrict__ out, const float* __restrict__ fcb) {
    int i = blockIdx.x * 256 + threadIdx.x;
    out[i] = fcb[0];
}

__device__ __forceinline__ void stage_chunk(const uint4* __restrict__ g, uint4* dst, int tid) {
    // 2048 units (32KB): each thread 4 x global_load_lds width 16.
    const uint4* g0 = g + tid;
    uint4* l0 = dst + (tid & ~63);
#pragma unroll
    for (int i = 0; i < 4; ++i)
        __builtin_amdgcn_global_load_lds(
            (const __attribute__((address_space(1))) void*)(g0 + i * 512),
            (__attribute__((address_space(3))) void*)(l0 + i * 512), 16, 0, 0);
}

// grid (32 colT, 16 rowT) x 512 thr (8 waves = 4 row x 2 col). 2 blocks/CU.
// XCD = blkid%8 = colT%8 -> W' slice L2-resident per XCD. h stores are
// NONTEMPORAL: avoid dirty-L2 scatter so next step's cross-XCD h reads hit
// clean L3 instead of the slow dirty-probe path. c/fd preloaded before K-loop.
__global__ __launch_bounds__(512, 4) void k_step(
    const u16* __restrict__ hin, u16* __restrict__ hout,
    float* __restrict__ c, const uint4* __restrict__ Wp,
    const float* __restrict__ fd, const float* __restrict__ Wih,
    const float* __restrict__ bih, const float* __restrict__ bhh,
    const float* __restrict__ fcw, const float* __restrict__ fcb,
    const float* __restrict__ p0, float* out, int t)
{
    __shared__ uint4 lbuf[2][2048];                  // 64 KB double-buffer
    __shared__ float pp[2][128];                     // fc partials (wc halves)

    const int tid  = threadIdx.x;
    const int lane = tid & 63;
    const int wave = tid >> 6;
    const int lr = lane & 15, lk = lane >> 4;
    const int wc = wave & 1, wr = wave >> 1;
    const int colT = blockIdx.x;                     // XCD = colT % 8
    const int rowT = blockIdx.y;
    const uint4* wbase = Wp + colT * 16384;
    const int j = colT * 32 + wc * 16 + lr;

    const u16* arow = hin + (size_t)(rowT * 128 + wr * 32 + lr) * HDIM + lk * 8;

    // ---- epilogue-operand prefetch (issued first; retire under the GEMM) ----
    float cold_pre[2][4], fd_pre[2][4];
#pragma unroll
    for (int ar = 0; ar < 2; ++ar)
#pragma unroll
        for (int r = 0; r < 4; ++r) {
            const int n = rowT * 128 + wr * 32 + ar * 16 + lk * 4 + r;
            cold_pre[ar][r] = c[(size_t)n * HDIM + j];
            fd_pre[ar][r]   = fd[n * TSTEPS + t];
        }

    f32x4 acc[2][4];
#pragma unroll
    for (int a = 0; a < 2; ++a)
#pragma unroll
        for (int g = 0; g < 4; ++g)
            acc[a][g] = (f32x4){0.f, 0.f, 0.f, 0.f};

    bf16x8 A0[2][4], A1[2][4];

    // Prologue: stage(0) then A(0); vmcnt(8) = preloads + stage(0) complete.
    stage_chunk(wbase, &lbuf[0][0], tid);
#pragma unroll
    for (int kcl = 0; kcl < 4; ++kcl) {
        A0[0][kcl] = *(const bf16x8*)(arow + kcl * 32);
        A1[0][kcl] = *(const bf16x8*)(arow + 16 * HDIM + kcl * 32);
    }
    vmcnt8();
    sbar();

#pragma unroll
    for (int ch = 0; ch < 8; ++ch) {
        if (ch < 7) {
            // Issue next chunk: 4 gload_lds + 8 A-loads = 12 VMEM ops.
            stage_chunk(wbase + (ch + 1) * 2048, &lbuf[(ch + 1) & 1][0], tid);
#pragma unroll
            for (int kcl = 0; kcl < 4; ++kcl) {
                const int kg = (ch + 1) * 4 + kcl;
                A0[(ch + 1) & 1][kcl] = *(const bf16x8*)(arow + kg * 32);
                A1[(ch + 1) & 1][kcl] = *(const bf16x8*)(arow + 16 * HDIM + kg * 32);
            }
            vmcnt12();            // chunk ch's 12 ops done; ch+1's stay in flight
        } else {
            vmcnt0();             // last chunk: drain
        }
        if (ch > 0) sbar();       // barrier A: all waves' stage(ch) landed

        const uint4* buf = &lbuf[ch & 1][0];
#pragma unroll
        for (int kcl = 0; kcl < 4; ++kcl) {
            bf16x8 a0 = A0[ch & 1][kcl];
            bf16x8 a1 = A1[ch & 1][kcl];
#pragma unroll
            for (int cf = 0; cf < 4; ++cf) {
                const int bc = cf * 32 + wc * 16 + lr;
                uint4 braw = buf[(kcl >> 1) * 1024 + bc * 8 +
                                 ((((kcl & 1) << 2) + lk) ^ (bc & 7))];
                bf16x8 bfr = __builtin_bit_cast(bf16x8, braw);
                acc[0][cf] = __builtin_amdgcn_mfma_f32_16x16x32_bf16(a0, bfr, acc[0][cf], 0, 0, 0);
                acc[1][cf] = __builtin_amdgcn_mfma_f32_16x16x32_bf16(a1, bfr, acc[1][cf], 0, 0, 0);
            }
        }
        if (ch < 7) {
            lgkm0();              // my ds_reads of buf[ch&1] complete
            sbar();               // barrier B: buf[ch&1] safe to overwrite
        }
    }

    // Epilogue: lane-local cell update; fc path folded into W'.
    float wx0[4], wx1[4], bs[4];
#pragma unroll
    for (int g = 0; g < 4; ++g) {
        int gr = g * HDIM + j;
        wx0[g] = Wih[2 * gr];
        wx1[g] = Wih[2 * gr + 1];
        bs[g]  = bih[gr] + bhh[gr];
    }
    const float fcwj = fcw[j];
    const float fcbv = fcb[0];

#pragma unroll
    for (int ar = 0; ar < 2; ++ar)
#pragma unroll
        for (int r = 0; r < 4; ++r) {
            const int n = rowT * 128 + wr * 32 + ar * 16 + lk * 4 + r;
            float pc   = (t == 0) ? (fcbv - p0[n]) : fcbv;   // prev-channel const
            float fdv  = fd_pre[ar][r];
            float gi = acc[ar][0][r] + wx1[0] * fdv + bs[0] + wx0[0] * pc;
            float gf = acc[ar][1][r] + wx1[1] * fdv + bs[1] + wx0[1] * pc;
            float gg = acc[ar][2][r] + wx1[2] * fdv + bs[2] + wx0[2] * pc;
            float go = acc[ar][3][r] + wx1[3] * fdv + bs[3] + wx0[3] * pc;
            float cn = sigf(gf) * cold_pre[ar][r] + sigf(gi) * tanhfast(gg);
            c[(size_t)n * HDIM + j] = cn;
            float hn = sigf(go) * tanhfast(cn);
            __builtin_nontemporal_store((u16)f2bf(hn), &hout[(size_t)n * HDIM + j]);
            float pr = fcwj * hn;
            pr += __shfl_xor(pr, 1);
            pr += __shfl_xor(pr, 2);
            pr += __shfl_xor(pr, 4);
            pr += __shfl_xor(pr, 8);
            if (lr == 0) pp[wc][wr * 32 + ar * 16 + lk * 4 + r] = pr;
        }
    __syncthreads();
    if (tid < 128) {
        int n = rowT * 128 + tid;
        atomicAdd(&out[n * TSTEPS + t], pp[0][tid] + pp[1][tid]);
    }
}

extern "C" void kernel_launch(void* const* d_in, const int* in_sizes, int n_in,
                              void* d_out, int out_size, void* d_ws, size_t ws_size,
                              hipStream_t stream) {
    const float* fd  = (const float*)d_in[0];
    const float* h0  = (const float*)d_in[1];
    const float* c0  = (const float*)d_in[2];
    const float* Wih = (const float*)d_in[3];
    const float* Whh = (const float*)d_in[4];
    const float* bih = (const float*)d_in[5];
    const float* bhh = (const float*)d_in[6];
    const float* fcw = (const float*)d_in[7];
    const float* fcb = (const float*)d_in[8];
    float* out = (float*)d_out;

    char* ws = (char*)d_ws;
    uint4* Wp   = (uint4*)(ws);
    u16*   hb0  = (u16*)(ws + 8388608);
    u16*   hb1  = (u16*)(ws + 12582912);
    float* cbuf = (float*)(ws + 16777216);
    float* p0   = (float*)(ws + 25165824);

    k_prep_w    <<<dim3(2048), dim3(256), 0, stream>>>(Whh, Wih, fcw, Wp);
    k_prep_state<<<dim3(2048), dim3(256), 0, stream>>>(h0, c0, hb0, cbuf);
    k_prep_p0   <<<dim3(512),  dim3(256), 0, stream>>>(h0, fcw, fcb, p0);
    k_init_out  <<<dim3(256),  dim3(256), 0, stream>>>(out, fcb);

    for (int t = 0; t < TSTEPS; ++t) {
        const u16* hi = (t & 1) ? hb1 : hb0;
        u16*       ho = (t & 1) ? hb0 : hb1;
        k_step<<<dim3(32, 16), dim3(512), 0, stream>>>(hi, ho, cbuf, Wp, fd,
                                                        Wih, bih, bhh, fcw, fcb,
                                                        p0, out, t);
    }
}

// Round 9
// 1443.943 us; speedup vs baseline: 1.2716x; 1.2716x over previous
//
#include <hip/hip_runtime.h>
#include <hip/hip_bf16.h>

#define TSTEPS 32
#define HDIM 1024

typedef __bf16 bf16x8 __attribute__((ext_vector_type(8)));
typedef float f32x4 __attribute__((ext_vector_type(4)));
typedef unsigned short u16;
typedef unsigned int u32;

__device__ __forceinline__ u32 f2bf(float f) {
    u32 u = __float_as_uint(f);
    return (u + 0x7FFFu + ((u >> 16) & 1u)) >> 16;   // RNE
}
__device__ __forceinline__ u32 pack2(float a, float b) {
    return f2bf(a) | (f2bf(b) << 16);
}
__device__ __forceinline__ float sigf(float x) { return 1.f / (1.f + __expf(-x)); }
__device__ __forceinline__ float tanhfast(float x) { return 1.f - 2.f / (1.f + __expf(2.f * x)); }

__device__ __forceinline__ void sbar()    { __builtin_amdgcn_s_barrier(); }
__device__ __forceinline__ void SCHED0()  { __builtin_amdgcn_sched_barrier(0); }
__device__ __forceinline__ void vmcnt12() { asm volatile("s_waitcnt vmcnt(12)" ::: "memory"); }
__device__ __forceinline__ void vmcnt8()  { asm volatile("s_waitcnt vmcnt(8)"  ::: "memory"); }
__device__ __forceinline__ void vmcnt0()  { asm volatile("s_waitcnt vmcnt(0)"  ::: "memory"); }
__device__ __forceinline__ void lgkm0()   { asm volatile("s_waitcnt lgkmcnt(0)" ::: "memory"); }

// Compile-time-offset 16B global load the compiler cannot sink/split.
template<int OFF>
__device__ __forceinline__ uint4 gload16o(const u16* p) {
    uint4 r;
    asm volatile("global_load_dwordx4 %0, %1, off offset:%2"
                 : "=v"(r) : "v"(p), "i"(OFF) : "memory");
    return r;
}

struct AR { uint4 r0, r1, r2, r3, r4, r5, r6, r7; };   // named: no dyn indexing

template<int KG>   // KG = ch*4; byte offsets (KG+kcl)*64, max 1984 < 4096
__device__ __forceinline__ void loadA(AR& a, const u16* arow0, const u16* arow1) {
    a.r0 = gload16o<(KG + 0) * 64>(arow0);
    a.r1 = gload16o<(KG + 1) * 64>(arow0);
    a.r2 = gload16o<(KG + 2) * 64>(arow0);
    a.r3 = gload16o<(KG + 3) * 64>(arow0);
    a.r4 = gload16o<(KG + 0) * 64>(arow1);
    a.r5 = gload16o<(KG + 1) * 64>(arow1);
    a.r6 = gload16o<(KG + 2) * 64>(arow1);
    a.r7 = gload16o<(KG + 3) * 64>(arow1);
}

__device__ __forceinline__ void mfma4(uint4 a0raw, uint4 a1raw, int kcl,
                                      const uint4* buf, int wc, int lr, int lk,
                                      f32x4 acc[2][4]) {
    bf16x8 a0 = __builtin_bit_cast(bf16x8, a0raw);
    bf16x8 a1 = __builtin_bit_cast(bf16x8, a1raw);
#pragma unroll
    for (int cf = 0; cf < 4; ++cf) {
        const int bc = cf * 32 + wc * 16 + lr;
        uint4 braw = buf[(kcl >> 1) * 1024 + bc * 8 + ((((kcl & 1) << 2) + lk) ^ (bc & 7))];
        bf16x8 bfr = __builtin_bit_cast(bf16x8, braw);
        acc[0][cf] = __builtin_amdgcn_mfma_f32_16x16x32_bf16(a0, bfr, acc[0][cf], 0, 0, 0);
        acc[1][cf] = __builtin_amdgcn_mfma_f32_16x16x32_bf16(a1, bfr, acc[1][cf], 0, 0, 0);
    }
}

template<int CH>
__device__ __forceinline__ void computeC(const AR& a, const uint4* lbase,
                                         int wc, int lr, int lk, f32x4 acc[2][4]) {
    const uint4* buf = lbase + (CH & 1) * 2048;
    mfma4(a.r0, a.r4, 0, buf, wc, lr, lk, acc);
    mfma4(a.r1, a.r5, 1, buf, wc, lr, lk, acc);
    mfma4(a.r2, a.r6, 2, buf, wc, lr, lk, acc);
    mfma4(a.r3, a.r7, 3, buf, wc, lr, lk, acc);
}

// ws: Wp (8MB) @0 | hb0 (4MB) @8M | hb1 (4MB) @12M | cbuf (8MB) @16M | p0 @24M

// Permuted bf16 W' with the fc path folded in (rank-1 update):
//   W'[jg][k] = Whh[jg][k] + Wih[jg,0]*fcW[k]
// Linear gload_lds staging => XOR-swizzled LDS image.
__global__ void k_prep_w(const float* __restrict__ W, const float* __restrict__ Wih,
                         const float* __restrict__ fcW, uint4* __restrict__ Wp) {
    int o = blockIdx.x * 256 + threadIdx.x;          // 524288 16B units
    int colT = o >> 14, c = (o >> 10) & 15, l = o & 1023;
    int bc = l >> 3, u = l & 7;
    int jg = ((bc >> 5) << 10) + colT * 32 + (bc & 31);
    int kk = c * 64 + ((u ^ (bc & 7)) << 3);
    const float4* src  = (const float4*)(W + (size_t)jg * HDIM + kk);
    const float4* fsrc = (const float4*)(fcW + kk);
    float wx = Wih[2 * jg];
    float4 lo = src[0], hi = src[1], fl = fsrc[0], fh = fsrc[1];
    lo.x += wx * fl.x; lo.y += wx * fl.y; lo.z += wx * fl.z; lo.w += wx * fl.w;
    hi.x += wx * fh.x; hi.y += wx * fh.y; hi.z += wx * fh.z; hi.w += wx * fh.w;
    uint4 pk = { pack2(lo.x, lo.y), pack2(lo.z, lo.w), pack2(hi.x, hi.y), pack2(hi.z, hi.w) };
    Wp[o] = pk;
}

__global__ void k_prep_state(const float* __restrict__ h0, const float* __restrict__ c0,
                             u16* __restrict__ hb, float* __restrict__ c) {
    int i = blockIdx.x * 256 + threadIdx.x;          // x4 elems
    float4 v = ((const float4*)h0)[i];
    ushort4 o = { (u16)f2bf(v.x), (u16)f2bf(v.y), (u16)f2bf(v.z), (u16)f2bf(v.w) };
    ((ushort4*)hb)[i] = o;
    ((float4*)c)[i] = ((const float4*)c0)[i];
}

// p0[n] = fcW . h0[n,:] + fcb  (t=0 correction for the folded fc path)
__global__ void k_prep_p0(const float* __restrict__ h0, const float* __restrict__ fcW,
                          const float* __restrict__ fcb, float* __restrict__ p0) {
    int n = blockIdx.x * 4 + (threadIdx.x >> 6);
    int lane = threadIdx.x & 63;
    const float* hr = h0 + (size_t)n * HDIM;
    float s = 0.f;
#pragma unroll
    for (int i = 0; i < 16; ++i)
        s += fcW[lane + 64 * i] * hr[lane + 64 * i];
    s += __shfl_xor(s, 1);  s += __shfl_xor(s, 2);  s += __shfl_xor(s, 4);
    s += __shfl_xor(s, 8);  s += __shfl_xor(s, 16); s += __shfl_xor(s, 32);
    if (lane == 0) p0[n] = s + fcb[0];
}

__global__ void k_init_out(float* __restrict__ out, const float* __restrict__ fcb) {
    int i = blockIdx.x * 256 + threadIdx.x;
    out[i] = fcb[0];
}

__device__ __forceinline__ void stage_chunk(const uint4* __restrict__ g, uint4* dst, int tid) {
    // 2048 units (32KB): each thread 4 x global_load_lds width 16.
    const uint4* g0 = g + tid;
    uint4* l0 = dst + (tid & ~63);
#pragma unroll
    for (int i = 0; i < 4; ++i)
        __builtin_amdgcn_global_load_lds(
            (const __attribute__((address_space(1))) void*)(g0 + i * 512),
            (__attribute__((address_space(3))) void*)(l0 + i * 512), 16, 0, 0);
}

// grid (32 colT, 16 rowT) x 512 thr (8 waves = 4 row x 2 col). 2 blocks/CU.
// XCD = blkid%8 = colT%8 -> W' slice L2-resident per XCD. K-loop: hand-
// sequenced 8-chunk pipeline; A prefetch in NAMED regs via asm loads with
// imm offsets (compiler-proof); counted vmcnt(12), sched_barrier after waits.
__global__ __launch_bounds__(512, 4) void k_step(
    const u16* __restrict__ hin, u16* __restrict__ hout,
    float* __restrict__ c, const uint4* __restrict__ Wp,
    const float* __restrict__ fd, const float* __restrict__ Wih,
    const float* __restrict__ bih, const float* __restrict__ bhh,
    const float* __restrict__ fcw, const float* __restrict__ fcb,
    const float* __restrict__ p0, float* out, int t)
{
    __shared__ uint4 lbuf[2][2048];                  // 64 KB double-buffer
    __shared__ float pp[2][128];                     // fc partials (wc halves)

    const int tid  = threadIdx.x;
    const int lane = tid & 63;
    const int wave = tid >> 6;
    const int lr = lane & 15, lk = lane >> 4;
    const int wc = wave & 1, wr = wave >> 1;
    const int colT = blockIdx.x;                     // XCD = colT % 8
    const int rowT = blockIdx.y;
    const uint4* wbase = Wp + colT * 16384;

    const u16* arow0 = hin + (size_t)(rowT * 128 + wr * 32 + lr) * HDIM + lk * 8;
    const u16* arow1 = arow0 + 16 * HDIM;

    f32x4 acc[2][4];
#pragma unroll
    for (int a = 0; a < 2; ++a)
#pragma unroll
        for (int g = 0; g < 4; ++g)
            acc[a][g] = (f32x4){0.f, 0.f, 0.f, 0.f};

    AR aE, aO;

    // Prologue: stage(0)[4 ops] + A(0)[8 ops]; vmcnt(8) => stage(0) done.
    stage_chunk(wbase, &lbuf[0][0], tid);
    loadA<0>(aE, arow0, arow1);
    vmcnt8(); SCHED0();
    sbar();

    // Chunk CH: [issue stage(CH+1)+A(CH+1) = 12 ops][vmcnt(12): CH's ops done]
    // [sbarA][compute CH][lgkm0][sbarB]. vmcnt(12) leaves CH+1's 12 in flight.
#define STEP_CHUNK(CH, CUR, NXT)                                               \
    stage_chunk(wbase + (CH + 1) * 2048, &lbuf[(CH + 1) & 1][0], tid);         \
    loadA<(CH + 1) * 4>(NXT, arow0, arow1);                                    \
    vmcnt12(); SCHED0();                                                       \
    if (CH > 0) sbar();                                                        \
    computeC<CH>(CUR, &lbuf[0][0], wc, lr, lk, acc);                           \
    lgkm0(); SCHED0();                                                         \
    sbar();

    STEP_CHUNK(0, aE, aO)
    STEP_CHUNK(1, aO, aE)
    STEP_CHUNK(2, aE, aO)
    STEP_CHUNK(3, aO, aE)
    STEP_CHUNK(4, aE, aO)
    STEP_CHUNK(5, aO, aE)
    STEP_CHUNK(6, aE, aO)
#undef STEP_CHUNK
    // CH = 7: nothing left to issue; drain and compute.
    vmcnt0(); SCHED0();
    sbar();
    computeC<7>(aO, &lbuf[0][0], wc, lr, lk, acc);

    // Epilogue: lane-local cell update; fc path folded into W'.
    const int j = colT * 32 + wc * 16 + lr;
    float wx0[4], wx1[4], bs[4];
#pragma unroll
    for (int g = 0; g < 4; ++g) {
        int gr = g * HDIM + j;
        wx0[g] = Wih[2 * gr];
        wx1[g] = Wih[2 * gr + 1];
        bs[g]  = bih[gr] + bhh[gr];
    }
    const float fcwj = fcw[j];
    const float fcbv = fcb[0];

#pragma unroll
    for (int ar = 0; ar < 2; ++ar)
#pragma unroll
        for (int r = 0; r < 4; ++r) {
            const int n = rowT * 128 + wr * 32 + ar * 16 + lk * 4 + r;
            float fdv  = fd[n * TSTEPS + t];
            float pc   = (t == 0) ? (fcbv - p0[n]) : fcbv;   // prev-channel const
            float gi = acc[ar][0][r] + wx1[0] * fdv + bs[0] + wx0[0] * pc;
            float gf = acc[ar][1][r] + wx1[1] * fdv + bs[1] + wx0[1] * pc;
            float gg = acc[ar][2][r] + wx1[2] * fdv + bs[2] + wx0[2] * pc;
            float go = acc[ar][3][r] + wx1[3] * fdv + bs[3] + wx0[3] * pc;
            float cold = c[(size_t)n * HDIM + j];
            float cn = sigf(gf) * cold + sigf(gi) * tanhfast(gg);
            c[(size_t)n * HDIM + j] = cn;
            float hn = sigf(go) * tanhfast(cn);
            hout[(size_t)n * HDIM + j] = (u16)f2bf(hn);
            float pr = fcwj * hn;
            pr += __shfl_xor(pr, 1);
            pr += __shfl_xor(pr, 2);
            pr += __shfl_xor(pr, 4);
            pr += __shfl_xor(pr, 8);
            if (lr == 0) pp[wc][wr * 32 + ar * 16 + lk * 4 + r] = pr;
        }
    __syncthreads();
    if (tid < 128) {
        int n = rowT * 128 + tid;
        atomicAdd(&out[n * TSTEPS + t], pp[0][tid] + pp[1][tid]);
    }
}

extern "C" void kernel_launch(void* const* d_in, const int* in_sizes, int n_in,
                              void* d_out, int out_size, void* d_ws, size_t ws_size,
                              hipStream_t stream) {
    const float* fd  = (const float*)d_in[0];
    const float* h0  = (const float*)d_in[1];
    const float* c0  = (const float*)d_in[2];
    const float* Wih = (const float*)d_in[3];
    const float* Whh = (const float*)d_in[4];
    const float* bih = (const float*)d_in[5];
    const float* bhh = (const float*)d_in[6];
    const float* fcw = (const float*)d_in[7];
    const float* fcb = (const float*)d_in[8];
    float* out = (float*)d_out;

    char* ws = (char*)d_ws;
    uint4* Wp   = (uint4*)(ws);
    u16*   hb0  = (u16*)(ws + 8388608);
    u16*   hb1  = (u16*)(ws + 12582912);
    float* cbuf = (float*)(ws + 16777216);
    float* p0   = (float*)(ws + 25165824);

    k_prep_w    <<<dim3(2048), dim3(256), 0, stream>>>(Whh, Wih, fcw, Wp);
    k_prep_state<<<dim3(2048), dim3(256), 0, stream>>>(h0, c0, hb0, cbuf);
    k_prep_p0   <<<dim3(512),  dim3(256), 0, stream>>>(h0, fcw, fcb, p0);
    k_init_out  <<<dim3(256),  dim3(256), 0, stream>>>(out, fcb);

    for (int t = 0; t < TSTEPS; ++t) {
        const u16* hi = (t & 1) ? hb1 : hb0;
        u16*       ho = (t & 1) ? hb0 : hb1;
        k_step<<<dim3(32, 16), dim3(512), 0, stream>>>(hi, ho, cbuf, Wp, fd,
                                                        Wih, bih, bhh, fcw, fcb,
                                                        p0, out, t);
    }
}

// Round 10
// 1387.005 us; speedup vs baseline: 1.3238x; 1.0411x over previous
//
#include <hip/hip_runtime.h>
#include <hip/hip_bf16.h>

#define TSTEPS 32
#define HDIM 1024

typedef __bf16 bf16x8 __attribute__((ext_vector_type(8)));
typedef float f32x4 __attribute__((ext_vector_type(4)));
typedef unsigned short u16;
typedef unsigned int u32;

__device__ __forceinline__ u32 f2bf(float f) {
    u32 u = __float_as_uint(f);
    return (u + 0x7FFFu + ((u >> 16) & 1u)) >> 16;   // RNE
}
__device__ __forceinline__ u32 pack2(float a, float b) {
    return f2bf(a) | (f2bf(b) << 16);
}
__device__ __forceinline__ float bf2f(u16 v) {
    return __uint_as_float(((u32)v) << 16);
}
__device__ __forceinline__ float sigf(float x) { return 1.f / (1.f + __expf(-x)); }
__device__ __forceinline__ float tanhfast(float x) { return 1.f - 2.f / (1.f + __expf(2.f * x)); }

__device__ __forceinline__ void sbar()    { __builtin_amdgcn_s_barrier(); }
__device__ __forceinline__ void vmcnt12() { asm volatile("s_waitcnt vmcnt(12)" ::: "memory"); }
__device__ __forceinline__ void vmcnt8()  { asm volatile("s_waitcnt vmcnt(8)"  ::: "memory"); }
__device__ __forceinline__ void vmcnt0()  { asm volatile("s_waitcnt vmcnt(0)"  ::: "memory"); }
__device__ __forceinline__ void lgkm0()   { asm volatile("s_waitcnt lgkmcnt(0)" ::: "memory"); }

// ws: Wp (8MB) @0 | hb0 (4MB) @8M | hb1 (4MB) @12M | cbuf bf16 (4MB) @16M | p0 @24M

// Permuted bf16 W' with the fc path folded in (rank-1 update):
//   W'[jg][k] = Whh[jg][k] + Wih[jg,0]*fcW[k]
// Linear gload_lds staging => XOR-swizzled LDS image.
__global__ void k_prep_w(const float* __restrict__ W, const float* __restrict__ Wih,
                         const float* __restrict__ fcW, uint4* __restrict__ Wp) {
    int o = blockIdx.x * 256 + threadIdx.x;          // 524288 16B units
    int colT = o >> 14, c = (o >> 10) & 15, l = o & 1023;
    int bc = l >> 3, u = l & 7;
    int jg = ((bc >> 5) << 10) + colT * 32 + (bc & 31);
    int kk = c * 64 + ((u ^ (bc & 7)) << 3);
    const float4* src  = (const float4*)(W + (size_t)jg * HDIM + kk);
    const float4* fsrc = (const float4*)(fcW + kk);
    float wx = Wih[2 * jg];
    float4 lo = src[0], hi = src[1], fl = fsrc[0], fh = fsrc[1];
    lo.x += wx * fl.x; lo.y += wx * fl.y; lo.z += wx * fl.z; lo.w += wx * fl.w;
    hi.x += wx * fh.x; hi.y += wx * fh.y; hi.z += wx * fh.z; hi.w += wx * fh.w;
    uint4 pk = { pack2(lo.x, lo.y), pack2(lo.z, lo.w), pack2(hi.x, hi.y), pack2(hi.z, hi.w) };
    Wp[o] = pk;
}

__global__ void k_prep_state(const float* __restrict__ h0, const float* __restrict__ c0,
                             u16* __restrict__ hb, u16* __restrict__ c) {
    int i = blockIdx.x * 256 + threadIdx.x;          // x4 elems
    float4 v = ((const float4*)h0)[i];
    float4 cv = ((const float4*)c0)[i];
    ushort4 o  = { (u16)f2bf(v.x),  (u16)f2bf(v.y),  (u16)f2bf(v.z),  (u16)f2bf(v.w) };
    ushort4 oc = { (u16)f2bf(cv.x), (u16)f2bf(cv.y), (u16)f2bf(cv.z), (u16)f2bf(cv.w) };
    ((ushort4*)hb)[i] = o;
    ((ushort4*)c)[i] = oc;
}

// p0[n] = fcW . h0[n,:] + fcb  (t=0 correction for the folded fc path)
__global__ void k_prep_p0(const float* __restrict__ h0, const float* __restrict__ fcW,
                          const float* __restrict__ fcb, float* __restrict__ p0) {
    int n = blockIdx.x * 4 + (threadIdx.x >> 6);
    int lane = threadIdx.x & 63;
    const float* hr = h0 + (size_t)n * HDIM;
    float s = 0.f;
#pragma unroll
    for (int i = 0; i < 16; ++i)
        s += fcW[lane + 64 * i] * hr[lane + 64 * i];
    s += __shfl_xor(s, 1);  s += __shfl_xor(s, 2);  s += __shfl_xor(s, 4);
    s += __shfl_xor(s, 8);  s += __shfl_xor(s, 16); s += __shfl_xor(s, 32);
    if (lane == 0) p0[n] = s + fcb[0];
}

__global__ void k_init_out(float* __restrict__ out, const float* __restrict__ fcb) {
    int i = blockIdx.x * 256 + threadIdx.x;
    out[i] = fcb[0];
}

__device__ __forceinline__ void stage_chunk(const uint4* __restrict__ g, uint4* dst, int tid) {
    // 2048 units (32KB): each thread 4 x global_load_lds width 16.
    const uint4* g0 = g + tid;
    uint4* l0 = dst + (tid & ~63);
#pragma unroll
    for (int i = 0; i < 4; ++i)
        __builtin_amdgcn_global_load_lds(
            (const __attribute__((address_space(1))) void*)(g0 + i * 512),
            (__attribute__((address_space(3))) void*)(l0 + i * 512), 16, 0, 0);
}

// grid 512 x 512 thr (8 waves = 4 row x 2 col). 2 blocks/CU.
// 2-D XCD supertiling: xcd = id%8 owns 8 colT x 8 rowT -> per-XCD L2 set
// = W' 2MB + h 2MB + c 0.5MB (vs 6MB with 1-D mapping) ~= L2 capacity.
// Block: 128 rows x 128 gate-cols. Lane owns all 4 gates of its (n,j).
// K-loop: counted-vmcnt pipelining (raw s_barrier + vmcnt(12)).
__global__ __launch_bounds__(512, 4) void k_step(
    const u16* __restrict__ hin, u16* __restrict__ hout,
    u16* __restrict__ c, const uint4* __restrict__ Wp,
    const float* __restrict__ fd, const float* __restrict__ Wih,
    const float* __restrict__ bih, const float* __restrict__ bhh,
    const float* __restrict__ fcw, const float* __restrict__ fcb,
    const float* __restrict__ p0, float* out, int t)
{
    __shared__ uint4 lbuf[2][2048];                  // 64 KB double-buffer
    __shared__ float pp[2][128];                     // fc partials (wc halves)

    const int tid  = threadIdx.x;
    const int lane = tid & 63;
    const int wave = tid >> 6;
    const int lr = lane & 15, lk = lane >> 4;
    const int wc = wave & 1, wr = wave >> 1;
    const int id  = blockIdx.x;
    const int xcd = id & 7, kk = id >> 3;            // HW: XCD = id % 8
    const int colT = ((xcd & 3) << 3) + (kk & 7);    // 4 colT-groups x
    const int rowT = ((xcd >> 2) << 3) + (kk >> 3);  // 2 rowT-groups
    const uint4* wbase = Wp + colT * 16384;

    const u16* arow = hin + (size_t)(rowT * 128 + wr * 32 + lr) * HDIM + lk * 8;

    f32x4 acc[2][4];
#pragma unroll
    for (int a = 0; a < 2; ++a)
#pragma unroll
        for (int g = 0; g < 4; ++g)
            acc[a][g] = (f32x4){0.f, 0.f, 0.f, 0.f};

    bf16x8 A0[2][4], A1[2][4];

    // Prologue: stage(0) then A(0); vmcnt(8) => stage(0) complete.
    stage_chunk(wbase, &lbuf[0][0], tid);
#pragma unroll
    for (int kcl = 0; kcl < 4; ++kcl) {
        A0[0][kcl] = *(const bf16x8*)(arow + kcl * 32);
        A1[0][kcl] = *(const bf16x8*)(arow + 16 * HDIM + kcl * 32);
    }
    vmcnt8();
    sbar();

#pragma unroll
    for (int ch = 0; ch < 8; ++ch) {
        if (ch < 7) {
            // Issue next chunk: 4 gload_lds + 8 A-loads = 12 VMEM ops.
            stage_chunk(wbase + (ch + 1) * 2048, &lbuf[(ch + 1) & 1][0], tid);
#pragma unroll
            for (int kcl = 0; kcl < 4; ++kcl) {
                const int kg = (ch + 1) * 4 + kcl;
                A0[(ch + 1) & 1][kcl] = *(const bf16x8*)(arow + kg * 32);
                A1[(ch + 1) & 1][kcl] = *(const bf16x8*)(arow + 16 * HDIM + kg * 32);
            }
            vmcnt12();            // chunk ch's 12 ops done; ch+1's stay in flight
        } else {
            vmcnt0();             // last chunk: drain
        }
        if (ch > 0) sbar();       // barrier A: all waves' stage(ch) landed

        const uint4* buf = &lbuf[ch & 1][0];
#pragma unroll
        for (int kcl = 0; kcl < 4; ++kcl) {
            bf16x8 a0 = A0[ch & 1][kcl];
            bf16x8 a1 = A1[ch & 1][kcl];
#pragma unroll
            for (int cf = 0; cf < 4; ++cf) {
                const int bc = cf * 32 + wc * 16 + lr;
                uint4 braw = buf[(kcl >> 1) * 1024 + bc * 8 +
                                 ((((kcl & 1) << 2) + lk) ^ (bc & 7))];
                bf16x8 bfr = __builtin_bit_cast(bf16x8, braw);
                acc[0][cf] = __builtin_amdgcn_mfma_f32_16x16x32_bf16(a0, bfr, acc[0][cf], 0, 0, 0);
                acc[1][cf] = __builtin_amdgcn_mfma_f32_16x16x32_bf16(a1, bfr, acc[1][cf], 0, 0, 0);
            }
        }
        if (ch < 7) {
            lgkm0();              // my ds_reads of buf[ch&1] complete
            sbar();               // barrier B: buf[ch&1] safe to overwrite
        }
    }

    // Epilogue: lane-local cell update; fc path folded into W'. c is bf16.
    const int j = colT * 32 + wc * 16 + lr;
    float wx0[4], wx1[4], bs[4];
#pragma unroll
    for (int g = 0; g < 4; ++g) {
        int gr = g * HDIM + j;
        wx0[g] = Wih[2 * gr];
        wx1[g] = Wih[2 * gr + 1];
        bs[g]  = bih[gr] + bhh[gr];
    }
    const float fcwj = fcw[j];
    const float fcbv = fcb[0];

#pragma unroll
    for (int ar = 0; ar < 2; ++ar)
#pragma unroll
        for (int r = 0; r < 4; ++r) {
            const int n = rowT * 128 + wr * 32 + ar * 16 + lk * 4 + r;
            float fdv  = fd[n * TSTEPS + t];
            float pc   = (t == 0) ? (fcbv - p0[n]) : fcbv;   // prev-channel const
            float gi = acc[ar][0][r] + wx1[0] * fdv + bs[0] + wx0[0] * pc;
            float gf = acc[ar][1][r] + wx1[1] * fdv + bs[1] + wx0[1] * pc;
            float gg = acc[ar][2][r] + wx1[2] * fdv + bs[2] + wx0[2] * pc;
            float go = acc[ar][3][r] + wx1[3] * fdv + bs[3] + wx0[3] * pc;
            float cold = bf2f(c[(size_t)n * HDIM + j]);
            float cn = sigf(gf) * cold + sigf(gi) * tanhfast(gg);
            c[(size_t)n * HDIM + j] = (u16)f2bf(cn);
            float hn = sigf(go) * tanhfast(cn);
            hout[(size_t)n * HDIM + j] = (u16)f2bf(hn);
            float pr = fcwj * hn;
            pr += __shfl_xor(pr, 1);
            pr += __shfl_xor(pr, 2);
            pr += __shfl_xor(pr, 4);
            pr += __shfl_xor(pr, 8);
            if (lr == 0) pp[wc][wr * 32 + ar * 16 + lk * 4 + r] = pr;
        }
    __syncthreads();
    if (tid < 128) {
        int n = rowT * 128 + tid;
        atomicAdd(&out[n * TSTEPS + t], pp[0][tid] + pp[1][tid]);
    }
}

extern "C" void kernel_launch(void* const* d_in, const int* in_sizes, int n_in,
                              void* d_out, int out_size, void* d_ws, size_t ws_size,
                              hipStream_t stream) {
    const float* fd  = (const float*)d_in[0];
    const float* h0  = (const float*)d_in[1];
    const float* c0  = (const float*)d_in[2];
    const float* Wih = (const float*)d_in[3];
    const float* Whh = (const float*)d_in[4];
    const float* bih = (const float*)d_in[5];
    const float* bhh = (const float*)d_in[6];
    const float* fcw = (const float*)d_in[7];
    const float* fcb = (const float*)d_in[8];
    float* out = (float*)d_out;

    char* ws = (char*)d_ws;
    uint4* Wp   = (uint4*)(ws);
    u16*   hb0  = (u16*)(ws + 8388608);
    u16*   hb1  = (u16*)(ws + 12582912);
    u16*   cbuf = (u16*)(ws + 16777216);
    float* p0   = (float*)(ws + 25165824);

    k_prep_w    <<<dim3(2048), dim3(256), 0, stream>>>(Whh, Wih, fcw, Wp);
    k_prep_state<<<dim3(2048), dim3(256), 0, stream>>>(h0, c0, hb0, cbuf);
    k_prep_p0   <<<dim3(512),  dim3(256), 0, stream>>>(h0, fcw, fcb, p0);
    k_init_out  <<<dim3(256),  dim3(256), 0, stream>>>(out, fcb);

    for (int t = 0; t < TSTEPS; ++t) {
        const u16* hi = (t & 1) ? hb1 : hb0;
        u16*       ho = (t & 1) ? hb0 : hb1;
        k_step<<<dim3(512), dim3(512), 0, stream>>>(hi, ho, cbuf, Wp, fd,
                                                     Wih, bih, bhh, fcw, fcb,
                                                     p0, out, t);
    }
}